// Round 9
// baseline (5906.856 us; speedup 1.0000x reference)
//
#include <hip/hip_runtime.h>
#include <cstdint>
#include <cstddef>

// LSTM: IC=HC=512, L=2, T=512, BS=64.  out = [T,64,512] fp32, hs/cs = [2,64,512] fp32.
// R10: LATENCY HIDING VIA INDEPENDENT BATCH CHAINS (exact math: batch rows are
//      independent recurrences).  Batch 64 -> 4 chains x 16 rows.  1-wave WGs
//      (64 threads, 128 WGs: 0..63 layer0 / 64..127 layer1); each WG owns 8
//      h-cols and processes the 4 chains ROUND-ROBIN.  Chain c's h(t-1) was
//      stored one full round (~4 chain-slots) earlier, so the MALL visibility
//      hop hides under the other chains' compute: ~4 steps per hop period.
//      Exchange protocol is byte-for-byte R5-proven: canary "data is the flag",
//      compiler-generated agent-scope relaxed atomics ONLY (no inline-asm vmem,
//      no flags, no counted vmcnt), fire-and-forget producer stores, bulk
//      masked retry.  Liveness identical to R5.

#define T_STEPS 512
#define WROW 1032   // LDS row stride (bf16 elems): 1024 + 8 pad
#define CAN64 0x7FC07FC07FC07FC0ULL

typedef float f32x4 __attribute__((ext_vector_type(4)));
typedef short s16x8 __attribute__((ext_vector_type(8)));

__device__ __forceinline__ unsigned short f2bf(float f) {
    unsigned int u = __builtin_bit_cast(unsigned int, f);
    u += 0x7FFFu + ((u >> 16) & 1u);          // round-to-nearest-even
    return (unsigned short)(u >> 16);
}
__device__ __forceinline__ float sig_(float x)  { return 1.0f / (1.0f + __expf(-x)); }
__device__ __forceinline__ float tanh_(float x) { return 1.0f - 2.0f / (__expf(2.0f * x) + 1.0f); }

// Coherent (agent-scope, MALL) 8B atomic load/store primitives (R5-proven).
__device__ __forceinline__ unsigned long long ld8(const unsigned short* p) {
    return __hip_atomic_load((unsigned long long*)p, __ATOMIC_RELAXED, __HIP_MEMORY_SCOPE_AGENT);
}
__device__ __forceinline__ void stc(unsigned short* p, s16x8 v) {
    ulonglong2 u = __builtin_bit_cast(ulonglong2, v);
    __hip_atomic_store((unsigned long long*)p,     u.x, __ATOMIC_RELAXED, __HIP_MEMORY_SCOPE_AGENT);
    __hip_atomic_store((unsigned long long*)p + 1, u.y, __ATOMIC_RELAXED, __HIP_MEMORY_SCOPE_AGENT);
}

// ---- prep kernels -------------------------------------------------------

__global__ void k_conv_bf16(const float* __restrict__ src, unsigned short* __restrict__ dst) {
    int i = (blockIdx.x * 256 + threadIdx.x) * 8;
    float4 a = *(const float4*)(src + i);
    float4 b = *(const float4*)(src + i + 4);
    s16x8 o;
    o[0]=(short)f2bf(a.x); o[1]=(short)f2bf(a.y); o[2]=(short)f2bf(a.z); o[3]=(short)f2bf(a.w);
    o[4]=(short)f2bf(b.x); o[5]=(short)f2bf(b.y); o[6]=(short)f2bf(b.z); o[7]=(short)f2bf(b.w);
    *(s16x8*)(dst + i) = o;
}

__global__ void k_transpose_w(const float* __restrict__ W0, const float* __restrict__ W1,
                              unsigned short* __restrict__ WT0, unsigned short* __restrict__ WT1) {
    __shared__ unsigned short tile[32][33];
    const float* W = blockIdx.z ? W1 : W0;
    unsigned short* WT = blockIdx.z ? WT1 : WT0;
    int n0 = blockIdx.x * 32, k0 = blockIdx.y * 32;
    int tx = threadIdx.x, ty = threadIdx.y;       // (32,8)
    #pragma unroll
    for (int i = 0; i < 4; i++)
        tile[ty + i*8][tx] = f2bf(W[(size_t)(k0 + ty + i*8) * 2048 + n0 + tx]);
    __syncthreads();
    #pragma unroll
    for (int i = 0; i < 4; i++)
        WT[(size_t)(n0 + ty + i*8) * 1024 + k0 + tx] = tile[tx][ty + i*8];
}

__global__ void k_hinit(const float* __restrict__ h0, unsigned short* __restrict__ hi0,
                        unsigned short* __restrict__ hi1) {
    int idx = blockIdx.x * 256 + threadIdx.x;   // 65536 total
    int layer = idx >> 15;
    int r = idx & 32767;
    int b = r >> 9;
    int j = r & 511;
    unsigned short v = f2bf(h0[layer * 512 + j]);
    unsigned short* d = layer ? hi1 : hi0;
    d[(size_t)((j >> 3) * 64 + b) * 8 + (j & 7)] = v;
}

// canary-fill h0s+h1s (64 MB contiguous): 16B per thread
__global__ void k_fill_canary(unsigned long long* __restrict__ dst) {
    size_t i = ((size_t)blockIdx.x * 256 + threadIdx.x) * 2;
    dst[i]     = CAN64;
    dst[i + 1] = CAN64;
}

// ---- fused persistent recurrence kernel ---------------------------------
// 128 one-wave WGs: blockIdx 0..63 = layer 0, 64..127 = layer 1.
// wg = blockIdx&63 owns hidden cols 8wg..8wg+7.  4 chains x 16 batch rows,
// processed round-robin inside the single wave.
// h streams: [t][jblock(64)][batchrow(64)][8] bf16; chain c owns rows 16c..16c+15.
__global__ __launch_bounds__(64, 1) void k_lstm_fused10(
    const unsigned short* __restrict__ xb,
    const unsigned short* __restrict__ hi0, const unsigned short* __restrict__ hi1,
    const unsigned short* __restrict__ WT0, const unsigned short* __restrict__ WT1,
    const float* __restrict__ b0, const float* __restrict__ b1,
    const float* __restrict__ c0,
    unsigned short* __restrict__ h0s, unsigned short* __restrict__ h1s,
    float* __restrict__ out, float* __restrict__ hs, float* __restrict__ cs)
{
    __shared__ unsigned short Wl[32][WROW];
    __shared__ unsigned short hst[16][8];

    const int isl1 = (int)(blockIdx.x >> 6);
    const int wg   = (int)(blockIdx.x & 63);
    const int tid  = (int)threadIdx.x;          // 0..63 (one wave)
    const int j0   = wg * 8;

    {   // stage this layer's W slice (32 gate-cols x K=1024), 64 threads
        const unsigned short* WT = isl1 ? WT1 : WT0;
        #pragma unroll
        for (int it = 0; it < 64; it++) {
            int idx = it * 64 + tid;             // 0..4095 chunk index
            int row = idx >> 7;                  // 0..31
            int ch  = idx & 127;                 // 0..127
            int gate = (row >> 4) * 2 + ((row & 15) >> 3);   // 0:f 1:i 2:o 3:g
            int gr = gate * 512 + j0 + (row & 7);
            *(s16x8*)(&Wl[row][ch * 8]) = *(const s16x8*)(WT + (size_t)gr * 1024 + ch * 8);
        }
    }
    __syncthreads();

    const int q  = tid >> 4;
    const int cc = tid & 15;
    const int jj = j0 + (cc & 7);

    const float* bias = isl1 ? b1 : b0;
    const float bt0 = (cc < 8) ? bias[jj] : bias[512 + jj];          // [f|i]
    const float bt1 = (cc < 8) ? bias[1024 + jj] : bias[1536 + jj];  // [o|g]
    float cst[4][4];
    {
        float ci = c0[isl1 * 512 + jj];
        #pragma unroll
        for (int c = 0; c < 4; c++)
            #pragma unroll
            for (int r = 0; r < 4; r++)
                cst[c][r] = ci;
    }

    if (!isl1) {
        // ================= layer 0 =================
        for (int t = 0; t < T_STEPS; t++) {
            const unsigned short* hb = t ? (h0s + (size_t)(t - 1) * 32768) : hi0;
            #pragma unroll
            for (int c = 0; c < 4; c++) {
                const int arow = c * 16 + cc;

                // 1. issue h0(t-1) sweep for this chain (bulk, pipelined)
                s16x8 ah[16];
                #pragma unroll
                for (int kk = 0; kk < 16; kk++) {
                    const unsigned short* p = hb + ((size_t)(kk * 4 + q) * 64 + arow) * 8;
                    ulonglong2 u; u.x = ld8(p); u.y = ld8(p + 4);
                    ah[kk] = __builtin_bit_cast(s16x8, u);
                }

                // 2. x-half MFMAs (cached loads; overlap the sweep flight)
                const unsigned short* xp = xb + (size_t)(t * 64 + arow) * 512 + q * 8;
                f32x4 a0  = {bt0, bt0, bt0, bt0};
                f32x4 a1  = {bt1, bt1, bt1, bt1};
                f32x4 a0b = {0.f, 0.f, 0.f, 0.f};
                f32x4 a1b = {0.f, 0.f, 0.f, 0.f};
                #pragma unroll
                for (int kk = 0; kk < 16; kk += 2) {       // K 0..511 : x(t)
                    s16x8 x0 = *(const s16x8*)(xp + kk * 32);
                    s16x8 x1 = *(const s16x8*)(xp + (kk + 1) * 32);
                    s16x8 w00 = *(const s16x8*)(&Wl[cc][kk * 32 + q * 8]);
                    s16x8 w10 = *(const s16x8*)(&Wl[16 + cc][kk * 32 + q * 8]);
                    a0  = __builtin_amdgcn_mfma_f32_16x16x32_bf16(x0, w00, a0, 0, 0, 0);
                    a1  = __builtin_amdgcn_mfma_f32_16x16x32_bf16(x0, w10, a1, 0, 0, 0);
                    s16x8 w01 = *(const s16x8*)(&Wl[cc][(kk + 1) * 32 + q * 8]);
                    s16x8 w11 = *(const s16x8*)(&Wl[16 + cc][(kk + 1) * 32 + q * 8]);
                    a0b = __builtin_amdgcn_mfma_f32_16x16x32_bf16(x1, w01, a0b, 0, 0, 0);
                    a1b = __builtin_amdgcn_mfma_f32_16x16x32_bf16(x1, w11, a1b, 0, 0, 0);
                }

                // 3. validate + bulk masked retry (R5-proven; steady state: no spin)
                bool ok = true;
                #pragma unroll
                for (int kk = 0; kk < 16; kk++) {
                    ulonglong2 u = __builtin_bit_cast(ulonglong2, ah[kk]);
                    ok = ok & (u.x != CAN64) & (u.y != CAN64);
                }
                while (!ok) {
                    __builtin_amdgcn_s_sleep(1);
                    ok = true;
                    #pragma unroll
                    for (int kk = 0; kk < 16; kk++) {
                        const unsigned short* p = hb + ((size_t)(kk * 4 + q) * 64 + arow) * 8;
                        ulonglong2 u; u.x = ld8(p); u.y = ld8(p + 4);
                        ok = ok & (u.x != CAN64) & (u.y != CAN64);
                        ah[kk] = __builtin_bit_cast(s16x8, u);
                    }
                }

                // 4. h-half MFMAs (K 512..1023)
                #pragma unroll
                for (int kk = 0; kk < 16; kk += 2) {
                    s16x8 w00 = *(const s16x8*)(&Wl[cc][(16 + kk) * 32 + q * 8]);
                    s16x8 w10 = *(const s16x8*)(&Wl[16 + cc][(16 + kk) * 32 + q * 8]);
                    a0  = __builtin_amdgcn_mfma_f32_16x16x32_bf16(ah[kk], w00, a0, 0, 0, 0);
                    a1  = __builtin_amdgcn_mfma_f32_16x16x32_bf16(ah[kk], w10, a1, 0, 0, 0);
                    s16x8 w01 = *(const s16x8*)(&Wl[cc][(17 + kk) * 32 + q * 8]);
                    s16x8 w11 = *(const s16x8*)(&Wl[16 + cc][(17 + kk) * 32 + q * 8]);
                    a0b = __builtin_amdgcn_mfma_f32_16x16x32_bf16(ah[kk + 1], w01, a0b, 0, 0, 0);
                    a1b = __builtin_amdgcn_mfma_f32_16x16x32_bf16(ah[kk + 1], w11, a1b, 0, 0, 0);
                }
                a0 = a0 + a0b;
                a1 = a1 + a1b;

                // 5. activation + stage + fire-and-forget flush
                #pragma unroll
                for (int r = 0; r < 4; r++) {
                    float z0 = a0[r], z1 = a1[r];
                    float p0 = __shfl_xor(z0, 8, 64);
                    float p1 = __shfl_xor(z1, 8, 64);
                    float zf = (cc < 8) ? z0 : p0;
                    float zi = (cc < 8) ? p0 : z0;
                    float zo = (cc < 8) ? z1 : p1;
                    float zg = (cc < 8) ? p1 : z1;
                    float fg = sig_(zf + 1.0f);            // FORGET_BIAS
                    float ig = sig_(zi);
                    float og = sig_(zo);
                    float gg = tanh_(zg);
                    float cn = cst[c][r] * fg + gg * ig;
                    cst[c][r] = cn;
                    float hv = og * tanh_(cn);
                    if (cc < 8) hst[q * 4 + r][cc] = f2bf(hv);
                    if (t == T_STEPS - 1) {
                        int b = c * 16 + q * 4 + r;
                        if (cc < 8) hs[(size_t)b * 512 + jj] = hv;
                        else        cs[(size_t)b * 512 + jj] = cn;
                    }
                }
                if (tid < 16)
                    stc(h0s + (size_t)t * 32768 + (size_t)wg * 512 + (size_t)(c * 16 + tid) * 8,
                        *(const s16x8*)(&hst[tid][0]));
            }
        }
    } else {
        // ================= layer 1 =================
        for (int t = 0; t < T_STEPS; t++) {
            const unsigned short* hb1 = t ? (h1s + (size_t)(t - 1) * 32768) : hi1;
            const unsigned short* hb0 = h0s + (size_t)t * 32768;
            #pragma unroll
            for (int c = 0; c < 4; c++) {
                const int arow = c * 16 + cc;

                // 1. issue h1(t-1) sweep, then h0(t) sweep (both pipelined)
                s16x8 ah1[16];
                #pragma unroll
                for (int kk = 0; kk < 16; kk++) {
                    const unsigned short* p = hb1 + ((size_t)(kk * 4 + q) * 64 + arow) * 8;
                    ulonglong2 u; u.x = ld8(p); u.y = ld8(p + 4);
                    ah1[kk] = __builtin_bit_cast(s16x8, u);
                }
                s16x8 ah0[16];
                #pragma unroll
                for (int kk = 0; kk < 16; kk++) {
                    const unsigned short* p = hb0 + ((size_t)(kk * 4 + q) * 64 + arow) * 8;
                    ulonglong2 u; u.x = ld8(p); u.y = ld8(p + 4);
                    ah0[kk] = __builtin_bit_cast(s16x8, u);
                }

                // 2. validate h1 + bulk masked retry
                bool ok1 = true;
                #pragma unroll
                for (int kk = 0; kk < 16; kk++) {
                    ulonglong2 u = __builtin_bit_cast(ulonglong2, ah1[kk]);
                    ok1 = ok1 & (u.x != CAN64) & (u.y != CAN64);
                }
                while (!ok1) {
                    __builtin_amdgcn_s_sleep(1);
                    ok1 = true;
                    #pragma unroll
                    for (int kk = 0; kk < 16; kk++) {
                        const unsigned short* p = hb1 + ((size_t)(kk * 4 + q) * 64 + arow) * 8;
                        ulonglong2 u; u.x = ld8(p); u.y = ld8(p + 4);
                        ok1 = ok1 & (u.x != CAN64) & (u.y != CAN64);
                        ah1[kk] = __builtin_bit_cast(s16x8, u);
                    }
                }

                // 3. h1-half MFMAs (K 512..1023) overlap the h0 flight
                f32x4 a0  = {bt0, bt0, bt0, bt0};
                f32x4 a1  = {bt1, bt1, bt1, bt1};
                f32x4 a0b = {0.f, 0.f, 0.f, 0.f};
                f32x4 a1b = {0.f, 0.f, 0.f, 0.f};
                #pragma unroll
                for (int kk = 0; kk < 16; kk += 2) {
                    s16x8 w00 = *(const s16x8*)(&Wl[cc][(16 + kk) * 32 + q * 8]);
                    s16x8 w10 = *(const s16x8*)(&Wl[16 + cc][(16 + kk) * 32 + q * 8]);
                    a0  = __builtin_amdgcn_mfma_f32_16x16x32_bf16(ah1[kk], w00, a0, 0, 0, 0);
                    a1  = __builtin_amdgcn_mfma_f32_16x16x32_bf16(ah1[kk], w10, a1, 0, 0, 0);
                    s16x8 w01 = *(const s16x8*)(&Wl[cc][(17 + kk) * 32 + q * 8]);
                    s16x8 w11 = *(const s16x8*)(&Wl[16 + cc][(17 + kk) * 32 + q * 8]);
                    a0b = __builtin_amdgcn_mfma_f32_16x16x32_bf16(ah1[kk + 1], w01, a0b, 0, 0, 0);
                    a1b = __builtin_amdgcn_mfma_f32_16x16x32_bf16(ah1[kk + 1], w11, a1b, 0, 0, 0);
                }

                // 4. validate h0 + bulk masked retry
                bool ok0 = true;
                #pragma unroll
                for (int kk = 0; kk < 16; kk++) {
                    ulonglong2 u = __builtin_bit_cast(ulonglong2, ah0[kk]);
                    ok0 = ok0 & (u.x != CAN64) & (u.y != CAN64);
                }
                while (!ok0) {
                    __builtin_amdgcn_s_sleep(1);
                    ok0 = true;
                    #pragma unroll
                    for (int kk = 0; kk < 16; kk++) {
                        const unsigned short* p = hb0 + ((size_t)(kk * 4 + q) * 64 + arow) * 8;
                        ulonglong2 u; u.x = ld8(p); u.y = ld8(p + 4);
                        ok0 = ok0 & (u.x != CAN64) & (u.y != CAN64);
                        ah0[kk] = __builtin_bit_cast(s16x8, u);
                    }
                }

                // 5. h0-half MFMAs (K 0..511)
                #pragma unroll
                for (int kk = 0; kk < 16; kk += 2) {
                    s16x8 w00 = *(const s16x8*)(&Wl[cc][kk * 32 + q * 8]);
                    s16x8 w10 = *(const s16x8*)(&Wl[16 + cc][kk * 32 + q * 8]);
                    a0  = __builtin_amdgcn_mfma_f32_16x16x32_bf16(ah0[kk], w00, a0, 0, 0, 0);
                    a1  = __builtin_amdgcn_mfma_f32_16x16x32_bf16(ah0[kk], w10, a1, 0, 0, 0);
                    s16x8 w01 = *(const s16x8*)(&Wl[cc][(kk + 1) * 32 + q * 8]);
                    s16x8 w11 = *(const s16x8*)(&Wl[16 + cc][(kk + 1) * 32 + q * 8]);
                    a0b = __builtin_amdgcn_mfma_f32_16x16x32_bf16(ah0[kk + 1], w01, a0b, 0, 0, 0);
                    a1b = __builtin_amdgcn_mfma_f32_16x16x32_bf16(ah0[kk + 1], w11, a1b, 0, 0, 0);
                }
                a0 = a0 + a0b;
                a1 = a1 + a1b;

                // 6. activation + stage + flush + out
                float ov[4];
                #pragma unroll
                for (int r = 0; r < 4; r++) {
                    float z0 = a0[r], z1 = a1[r];
                    float p0 = __shfl_xor(z0, 8, 64);
                    float p1 = __shfl_xor(z1, 8, 64);
                    float zf = (cc < 8) ? z0 : p0;
                    float zi = (cc < 8) ? p0 : z0;
                    float zo = (cc < 8) ? z1 : p1;
                    float zg = (cc < 8) ? p1 : z1;
                    float fg = sig_(zf + 1.0f);            // FORGET_BIAS
                    float ig = sig_(zi);
                    float og = sig_(zo);
                    float gg = tanh_(zg);
                    float cn = cst[c][r] * fg + gg * ig;
                    cst[c][r] = cn;
                    float hv = og * tanh_(cn);
                    ov[r] = hv;
                    if (cc < 8) hst[q * 4 + r][cc] = f2bf(hv);
                    if (t == T_STEPS - 1) {
                        int b = c * 16 + q * 4 + r;
                        if (cc < 8) hs[(size_t)(64 + b) * 512 + jj] = hv;
                        else        cs[(size_t)(64 + b) * 512 + jj] = cn;
                    }
                }
                if (tid < 16)
                    stc(h1s + (size_t)t * 32768 + (size_t)wg * 512 + (size_t)(c * 16 + tid) * 8,
                        *(const s16x8*)(&hst[tid][0]));

                // out f32 stores: cached path, after the flush
                if (cc >= 8) {
                    #pragma unroll
                    for (int r = 0; r < 4; r++)
                        out[((size_t)(t * 64 + c * 16 + q * 4 + r)) * 512 + jj] = ov[r];
                }
            }
        }
    }
}

// ---- launch -------------------------------------------------------------

extern "C" void kernel_launch(void* const* d_in, const int* in_sizes, int n_in,
                              void* d_out, int out_size, void* d_ws, size_t ws_size,
                              hipStream_t stream) {
    const float* x  = (const float*)d_in[0];
    const float* W0 = (const float*)d_in[1];
    const float* b0 = (const float*)d_in[2];
    const float* W1 = (const float*)d_in[3];
    const float* b1 = (const float*)d_in[4];
    const float* h0 = (const float*)d_in[5];
    const float* c0 = (const float*)d_in[6];
    float* out = (float*)d_out;

    char* ws = (char*)d_ws;
    unsigned short* xb  = (unsigned short*)(ws);                               // 33,554,432 B
    unsigned short* h0s = (unsigned short*)(ws + 33554432);                    // 33,554,432 B
    unsigned short* h1s = (unsigned short*)(ws + 2 * 33554432);                // 33,554,432 B
    unsigned short* WT0 = (unsigned short*)(ws + 3 * 33554432);                //  4,194,304 B
    unsigned short* WT1 = (unsigned short*)(ws + 3 * 33554432 + 4194304);      //  4,194,304 B
    unsigned short* hi0 = (unsigned short*)(ws + 3 * 33554432 + 2 * 4194304);            // 65,536 B
    unsigned short* hi1 = (unsigned short*)(ws + 3 * 33554432 + 2 * 4194304 + 65536);    // 65,536 B

    // canary-fill the h exchange ring (h0s + h1s are contiguous: 64 MB)
    k_fill_canary<<<16384, 256, 0, stream>>>((unsigned long long*)h0s);
    k_conv_bf16<<<8192, 256, 0, stream>>>(x, xb);
    k_transpose_w<<<dim3(64, 32, 2), dim3(32, 8), 0, stream>>>(W0, W1, WT0, WT1);
    k_hinit<<<256, 256, 0, stream>>>(h0, hi0, hi1);

    float* hs = out + 16777216;            // [2][64][512]
    float* cs = hs + 65536;                // [2][64][512]
    k_lstm_fused10<<<128, 64, 0, stream>>>(xb, hi0, hi1, WT0, WT1, b0, b1, c0,
                                           h0s, h1s, out, hs, cs);
}